// Round 11
// baseline (299.529 us; speedup 1.0000x reference)
//
#include <hip/hip_runtime.h>
#include <hip/hip_bf16.h>

// RGCN 2-layer forward. LDS-histogram bucket sort with atomic bucket
// allocation (r9 structure). Round-11 = ONE isolated change: l2 restructured
// to 16 edges x 4 h-lanes (the layout that won in l1/r8). r10 taught that
// l2's bank conflicts were hidden (halving them changed nothing): l2 is
// chain-latency bound (sorted->x dependent gathers, 4 iters/wave, 4 x-loads
// per lane-edge). New layout: 1x 16B x-load per lane-edge (inv pre-folded),
// 8 ds_read_b128 partial dots (naturally <=2-way banks: c*16+hp*4 spans are
// disjoint within an edge quad), 2 iters/wave, unroll-2 MLP.
// sorted word = src | rel<<16 | min(cnt,2047)<<21.

constexpr int Nn = 50000;
constexpr int Hh = 16;
constexpr int Cc = 8;
constexpr int Ee = 1600000;
constexpr int CHUNK = 4096;                    // edges per chunk
constexpr int NC = (Ee + CHUNK - 1) / CHUNK;   // 391 chunks
constexpr int DSH = 7;                         // bucket = dst >> 7 (128 dsts)
constexpr unsigned DLOWM = 127u;
constexpr int NBKT = (Nn + 127) / 128;         // 391 buckets
constexpr int STRIDE = 5120;                   // bucket region (16 sigma margin)

__device__ __forceinline__ float b2f(__hip_bfloat16 v) { return __bfloat162float(v); }
__device__ __forceinline__ float bs2f(unsigned short u) {
    return __uint_as_float(((unsigned)u) << 16);   // bf16 bits -> f32
}

// --- 1. merged count + atomic-reserve + scatter (one kernel, 512 threads) -----
__global__ __launch_bounds__(512) void scat_kernel(const int* __restrict__ src,
                                                   const int* __restrict__ dst,
                                                   const int* __restrict__ et,
                                                   unsigned* __restrict__ gcnt,
                                                   unsigned* __restrict__ rec,
                                                   const unsigned short* __restrict__ w1s,
                                                   int* __restrict__ flag) {
    __shared__ unsigned hb[NBKT];   // per-bucket count in this chunk
    __shared__ unsigned bb[NBKT];   // reserved global base
    __shared__ unsigned rk[NBKT];   // rank counter for scatter pass
    int c = blockIdx.x, t = threadIdx.x;
    if (c == 0 && t == 0) {         // folded dtype sniff
        int hits = 0;
        for (int i = 0; i < 64; ++i) {
            unsigned short u = w1s[2 * i];
            int e = (u >> 7) & 0xFF;
            if (e >= 100 && e <= 130) ++hits;
        }
        *flag = (hits >= 32) ? 1 : 0;   // 1 = bf16, 0 = fp32
    }
    for (int i = t; i < NBKT; i += 512) { hb[i] = 0; rk[i] = 0; }
    __syncthreads();
    int base = c * CHUNK;
    int n = min(CHUNK, Ee - base);
    for (int i = t; i < n; i += 512)
        atomicAdd(&hb[((unsigned)dst[base + i]) >> DSH], 1u);
    __syncthreads();
    for (int cell = t; cell < NBKT; cell += 512) {
        unsigned cv = hb[cell];
        if (cv)   // one device atomic per (chunk, nonzero bucket): ~150K total
            bb[cell] = (unsigned)cell * STRIDE + atomicAdd(&gcnt[cell], cv);
    }
    __syncthreads();
    for (int i = t; i < n; i += 512) {
        int e = base + i;
        unsigned d = (unsigned)dst[e];
        unsigned r = (unsigned)et[e];
        unsigned sv = (unsigned)src[e];
        unsigned bkt = d >> DSH;
        unsigned rank = atomicAdd(&rk[bkt], 1u);
        rec[bb[bkt] + rank] = sv | (r << 16) | ((d & DLOWM) << 21);  // src16|rel5|dlow7
    }
}

// --- 2. per-bucket counting sort: 128 dst x 32 rel cells in LDS (512t) --------
__global__ __launch_bounds__(512) void sortD_kernel(const unsigned* __restrict__ rec,
                                                    const unsigned* __restrict__ gcnt,
                                                    unsigned* __restrict__ sorted,
                                                    int* __restrict__ offs,
                                                    unsigned short* __restrict__ deg16) {
    __shared__ unsigned cnt[128 * 33];
    __shared__ unsigned sb[128 * 33];
    __shared__ int l2s[2];
    int b = blockIdx.x, t = threadIdx.x, lane = t & 63, wv = t >> 6;
    for (int i = t; i < 128 * 33; i += 512) cnt[i] = 0;
    __syncthreads();
    unsigned rb = (unsigned)b * STRIDE;
    int n = (int)min(gcnt[b], (unsigned)STRIDE);
    for (int i = t; i < n; i += 512) {
        unsigned w = rec[rb + i];
        atomicAdd(&cnt[((w >> 21) & 127u) * 33 + ((w >> 16) & 31u)], 1u);
    }
    __syncthreads();
    int deg = 0;
    if (t < 128) {
#pragma unroll
        for (int r = 0; r < 32; ++r) {
            unsigned cc = cnt[t * 33 + r];
            sb[t * 33 + r] = (unsigned)deg;
            deg += (int)cc;
        }
    }
    int s = deg;   // waves 0-1 carry real values; others zero/unused
#pragma unroll
    for (int o = 1; o < 64; o <<= 1) { int u = __shfl_up(s, o, 64); if (lane >= o) s += u; }
    if (lane == 63 && wv < 2) l2s[wv] = s;
    __syncthreads();
    if (t < 128) {
        int excl = s - deg + (wv == 1 ? l2s[0] : 0);
        unsigned ab = rb + (unsigned)excl;
        int d = b * 128 + t;
        if (d < Nn) { offs[d] = (int)ab; deg16[d] = (unsigned short)deg; }
#pragma unroll
        for (int r = 0; r < 32; ++r) sb[t * 33 + r] += ab;
    }
    __syncthreads();
    for (int i = t; i < n; i += 512) {
        unsigned w = rec[rb + i];
        unsigned dlow = (w >> 21) & 127u, rel = (w >> 16) & 31u, sv = w & 0xFFFFu;
        int cell = (int)dlow * 33 + (int)rel;
        unsigned pos = atomicAdd(&sb[cell], 1u);
        unsigned cc = cnt[cell];
        if (cc > 2047u) cc = 2047u;
        sorted[pos] = sv | (rel << 16) | (cc << 21);
    }
}

// --- 3. layer 1: one wave per dst, 16 edges x 4 h-lanes (8B gathers) ----------
__global__ __launch_bounds__(256) void l1_kernel(const unsigned* __restrict__ sorted,
                                                 const int* __restrict__ offs,
                                                 const unsigned short* __restrict__ deg16,
                                                 const void* __restrict__ w1,
                                                 const void* __restrict__ root1,
                                                 const void* __restrict__ b1,
                                                 const int* __restrict__ flag,
                                                 float* __restrict__ x) {
    int tid = threadIdx.x, w = tid >> 6, lane = tid & 63;
    int ep = lane >> 2, hp = lane & 3;
    int isbf = *flag;
    int d = blockIdx.x * 4 + w;                  // 12500*4 == Nn
    int off = offs[d], deg = (int)deg16[d];
    float a0 = 0.f, a1 = 0.f, a2 = 0.f, a3 = 0.f;
    if (isbf) {
#pragma unroll 2
        for (int i = ep; i < deg; i += 16) {
            unsigned p = sorted[off + i];
            int cnt = p >> 21, rel = (p >> 16) & 31, s = p & 0xFFFF;
            float inv = __builtin_amdgcn_rcpf((float)cnt);
            ushort4 v = ((const ushort4*)w1)[((size_t)rel * Nn + s) * 4 + hp];
            a0 += inv * bs2f(v.x); a1 += inv * bs2f(v.y);
            a2 += inv * bs2f(v.z); a3 += inv * bs2f(v.w);
        }
    } else {
#pragma unroll 2
        for (int i = ep; i < deg; i += 16) {
            unsigned p = sorted[off + i];
            int cnt = p >> 21, rel = (p >> 16) & 31, s = p & 0xFFFF;
            float inv = __builtin_amdgcn_rcpf((float)cnt);
            float4 v = ((const float4*)w1)[((size_t)rel * Nn + s) * 4 + hp];
            a0 += inv * v.x; a1 += inv * v.y; a2 += inv * v.z; a3 += inv * v.w;
        }
    }
#pragma unroll
    for (int o = 4; o < 64; o <<= 1) {
        a0 += __shfl_xor(a0, o, 64);
        a1 += __shfl_xor(a1, o, 64);
        a2 += __shfl_xor(a2, o, 64);
        a3 += __shfl_xor(a3, o, 64);
    }
    if (ep == 0) {   // lanes 0..3 hold h = hp*4 .. hp*4+3
        float r0, r1, r2, r3, bb0, bb1, bb2, bb3;
        if (isbf) {
            ushort4 rv = ((const ushort4*)root1)[(size_t)d * 4 + hp];
            ushort4 bv = ((const ushort4*)b1)[hp];
            r0 = bs2f(rv.x); r1 = bs2f(rv.y); r2 = bs2f(rv.z); r3 = bs2f(rv.w);
            bb0 = bs2f(bv.x); bb1 = bs2f(bv.y); bb2 = bs2f(bv.z); bb3 = bs2f(bv.w);
        } else {
            float4 rv = ((const float4*)root1)[(size_t)d * 4 + hp];
            float4 bv = ((const float4*)b1)[hp];
            r0 = rv.x; r1 = rv.y; r2 = rv.z; r3 = rv.w;
            bb0 = bv.x; bb1 = bv.y; bb2 = bv.z; bb3 = bv.w;
        }
        float v0 = a0 + r0 + bb0, v1 = a1 + r1 + bb1;
        float v2 = a2 + r2 + bb2, v3 = a3 + r3 + bb3;
        *(float4*)(x + (size_t)d * Hh + hp * 4) =
            make_float4(v0 > 0.f ? v0 : 0.f, v1 > 0.f ? v1 : 0.f,
                        v2 > 0.f ? v2 : 0.f, v3 > 0.f ? v3 : 0.f);
    }
}

// --- 4. layer 2 + epilogue: one wave per dst, 16 edges x 4 h-lanes ------------
// lane(ep,hp): loads hp-th 16B quarter of x[src] (inv pre-folded), computes 8
// per-class partial dots from w2s (8 x ds_read_b128; <=2-way banks), butterfly
// sums over h-quarters+edges, lanes 0-7 finish root2/bias/logsoftmax.
__global__ __launch_bounds__(256) void l2_kernel(const unsigned* __restrict__ sorted,
                                                 const int* __restrict__ offs,
                                                 const unsigned short* __restrict__ deg16,
                                                 const float* __restrict__ x,
                                                 const void* __restrict__ w2,
                                                 const void* __restrict__ root2,
                                                 const void* __restrict__ b2v,
                                                 const int* __restrict__ flag,
                                                 void* __restrict__ out) {
    __shared__ float w2s[32 * 132];   // [rel]*132 + c*16 + h
    __shared__ float rsh[128];        // root2 [h*8+c]
    __shared__ float b2sh[8];
    int tid = threadIdx.x, w = tid >> 6, lane = tid & 63;
    int isbf = *flag;
    {
        int r = tid >> 3, cc = tid & 7;
        if (isbf) {
            const __hip_bfloat16* W = (const __hip_bfloat16*)w2 + r * 128 + cc;
#pragma unroll
            for (int h = 0; h < 16; ++h) w2s[r * 132 + cc * 16 + h] = b2f(W[h * 8]);
        } else {
            const float* W = (const float*)w2 + r * 128 + cc;
#pragma unroll
            for (int h = 0; h < 16; ++h) w2s[r * 132 + cc * 16 + h] = W[h * 8];
        }
    }
    if (tid < 128) rsh[tid] = isbf ? b2f(((const __hip_bfloat16*)root2)[tid])
                                   : ((const float*)root2)[tid];
    if (tid < 8)   b2sh[tid] = isbf ? b2f(((const __hip_bfloat16*)b2v)[tid])
                                    : ((const float*)b2v)[tid];
    __syncthreads();
    int ep = lane >> 2, hp = lane & 3;
    int d = blockIdx.x * 4 + w;
    int off = offs[d], deg = (int)deg16[d];
    float a0 = 0.f, a1 = 0.f, a2 = 0.f, a3 = 0.f;
    float a4 = 0.f, a5 = 0.f, a6 = 0.f, a7 = 0.f;
#pragma unroll 2
    for (int i = ep; i < deg; i += 16) {
        unsigned p = sorted[off + i];
        int cnt = p >> 21, rel = (p >> 16) & 31, s = p & 0xFFFF;
        float inv = __builtin_amdgcn_rcpf((float)cnt);
        float4 xq = ((const float4*)(x + (size_t)s * Hh))[hp];
        xq.x *= inv; xq.y *= inv; xq.z *= inv; xq.w *= inv;
        const float* wb = w2s + rel * 132 + hp * 4;
        float4 w0 = *(const float4*)(wb);
        float4 w1v = *(const float4*)(wb + 16);
        float4 w2v = *(const float4*)(wb + 32);
        float4 w3 = *(const float4*)(wb + 48);
        float4 w4 = *(const float4*)(wb + 64);
        float4 w5 = *(const float4*)(wb + 80);
        float4 w6 = *(const float4*)(wb + 96);
        float4 w7 = *(const float4*)(wb + 112);
        a0 += xq.x*w0.x + xq.y*w0.y + xq.z*w0.z + xq.w*w0.w;
        a1 += xq.x*w1v.x + xq.y*w1v.y + xq.z*w1v.z + xq.w*w1v.w;
        a2 += xq.x*w2v.x + xq.y*w2v.y + xq.z*w2v.z + xq.w*w2v.w;
        a3 += xq.x*w3.x + xq.y*w3.y + xq.z*w3.z + xq.w*w3.w;
        a4 += xq.x*w4.x + xq.y*w4.y + xq.z*w4.z + xq.w*w4.w;
        a5 += xq.x*w5.x + xq.y*w5.y + xq.z*w5.z + xq.w*w5.w;
        a6 += xq.x*w6.x + xq.y*w6.y + xq.z*w6.z + xq.w*w6.w;
        a7 += xq.x*w7.x + xq.y*w7.y + xq.z*w7.z + xq.w*w7.w;
    }
#pragma unroll
    for (int o = 1; o < 64; o <<= 1) {
        a0 += __shfl_xor(a0, o, 64); a1 += __shfl_xor(a1, o, 64);
        a2 += __shfl_xor(a2, o, 64); a3 += __shfl_xor(a3, o, 64);
        a4 += __shfl_xor(a4, o, 64); a5 += __shfl_xor(a5, o, 64);
        a6 += __shfl_xor(a6, o, 64); a7 += __shfl_xor(a7, o, 64);
    }
    if (lane < 8) {
        int c = lane;
        float acc = (c == 0) ? a0 : (c == 1) ? a1 : (c == 2) ? a2 : (c == 3) ? a3
                  : (c == 4) ? a4 : (c == 5) ? a5 : (c == 6) ? a6 : a7;
        const float4* xr = (const float4*)(x + (size_t)d * Hh);
        float4 x0 = xr[0], x1 = xr[1], x2 = xr[2], x3 = xr[3];
        float xv[16] = {x0.x,x0.y,x0.z,x0.w, x1.x,x1.y,x1.z,x1.w,
                        x2.x,x2.y,x2.z,x2.w, x3.x,x3.y,x3.z,x3.w};
        float v = acc + b2sh[c];
#pragma unroll
        for (int h = 0; h < 16; ++h) v += xv[h] * rsh[h * 8 + c];
        float m = v;
#pragma unroll
        for (int o = 1; o < 8; o <<= 1) m = fmaxf(m, __shfl_xor(m, o, 8));
        float ssum = __expf(v - m);
#pragma unroll
        for (int o = 1; o < 8; o <<= 1) ssum += __shfl_xor(ssum, o, 8);
        float res = v - m - __logf(ssum);
        if (isbf) ((__hip_bfloat16*)out)[(size_t)d * Cc + c] = __float2bfloat16(res);
        else      ((float*)out)[(size_t)d * Cc + c] = res;
    }
}

extern "C" void kernel_launch(void* const* d_in, const int* in_sizes, int n_in,
                              void* d_out, int out_size, void* d_ws, size_t ws_size,
                              hipStream_t stream) {
    const int* edge_index = (const int*)d_in[0];     // [2, E]
    const int* src = edge_index;
    const int* dst = edge_index + Ee;
    const int* et  = (const int*)d_in[1];            // [E]
    const void* w1    = d_in[2];  // [R,N,H]
    const void* root1 = d_in[3];  // [N,H]
    const void* b1    = d_in[4];  // [H]
    const void* w2    = d_in[5];  // [R,H,C]
    const void* root2 = d_in[6];  // [H,C]
    const void* b2    = d_in[7];  // [C]

    // ws (u32 words, ~16.3 MB): rec[NBKT*STRIDE] (x[800000] overlays after
    // sortD) | sorted[NBKT*STRIDE] | gcnt[NBKT] | offs[Nn] | deg16[Nn u16] |
    // flag. Only gcnt needs zeroing (1.6 KB).
    unsigned* rec    = (unsigned*)d_ws;
    unsigned* sorted = rec + (size_t)NBKT * STRIDE;
    unsigned* gcnt   = sorted + (size_t)NBKT * STRIDE;
    int* offs        = (int*)(gcnt + NBKT);
    unsigned short* deg16 = (unsigned short*)(offs + Nn);
    int* flag        = (int*)(deg16 + Nn + 2);
    float* x         = (float*)rec;    // overlay: rec dead after sortD

    hipMemsetAsync(gcnt, 0, NBKT * sizeof(unsigned), stream);
    scat_kernel<<<NC, 512, 0, stream>>>(src, dst, et, gcnt, rec,
                                        (const unsigned short*)w1, flag);
    sortD_kernel<<<NBKT, 512, 0, stream>>>(rec, gcnt, sorted, offs, deg16);
    l1_kernel<<<Nn / 4, 256, 0, stream>>>(sorted, offs, deg16, w1, root1, b1, flag, x);
    l2_kernel<<<Nn / 4, 256, 0, stream>>>(sorted, offs, deg16, x, w2, root2, b2, flag, d_out);
}

// Round 12
// 284.290 us; speedup vs baseline: 1.0536x; 1.0536x over previous
//
#include <hip/hip_runtime.h>
#include <hip/hip_bf16.h>

// RGCN 2-layer forward. LDS-histogram bucket sort with atomic bucket
// allocation (r9 structure, 291.6us session best). Round-12 = ONE isolated
// change vs r9: l2 block owns 16 dsts (each wave loops 4 dsts), grid
// 12500->3125, amortizing the 16KB w2s staging prologue 4x. r10/r11 lessons:
// l2's LDS bank conflicts are hidden (halving them or restructuring the dot
// both failed); the r9 8-edge x 8-class inner loop is optimal — the residual
// cost is the per-block staging, so amortize it.
// sorted word = src | rel<<16 | min(cnt,2047)<<21.

constexpr int Nn = 50000;
constexpr int Hh = 16;
constexpr int Cc = 8;
constexpr int Ee = 1600000;
constexpr int CHUNK = 4096;                    // edges per chunk
constexpr int NC = (Ee + CHUNK - 1) / CHUNK;   // 391 chunks
constexpr int DSH = 7;                         // bucket = dst >> 7 (128 dsts)
constexpr unsigned DLOWM = 127u;
constexpr int NBKT = (Nn + 127) / 128;         // 391 buckets
constexpr int STRIDE = 5120;                   // bucket region (16 sigma margin)

__device__ __forceinline__ float b2f(__hip_bfloat16 v) { return __bfloat162float(v); }
__device__ __forceinline__ float bs2f(unsigned short u) {
    return __uint_as_float(((unsigned)u) << 16);   // bf16 bits -> f32
}

// --- 1. merged count + atomic-reserve + scatter (one kernel, 512 threads) -----
__global__ __launch_bounds__(512) void scat_kernel(const int* __restrict__ src,
                                                   const int* __restrict__ dst,
                                                   const int* __restrict__ et,
                                                   unsigned* __restrict__ gcnt,
                                                   unsigned* __restrict__ rec,
                                                   const unsigned short* __restrict__ w1s,
                                                   int* __restrict__ flag) {
    __shared__ unsigned hb[NBKT];   // per-bucket count in this chunk
    __shared__ unsigned bb[NBKT];   // reserved global base
    __shared__ unsigned rk[NBKT];   // rank counter for scatter pass
    int c = blockIdx.x, t = threadIdx.x;
    if (c == 0 && t == 0) {         // folded dtype sniff
        int hits = 0;
        for (int i = 0; i < 64; ++i) {
            unsigned short u = w1s[2 * i];
            int e = (u >> 7) & 0xFF;
            if (e >= 100 && e <= 130) ++hits;
        }
        *flag = (hits >= 32) ? 1 : 0;   // 1 = bf16, 0 = fp32
    }
    for (int i = t; i < NBKT; i += 512) { hb[i] = 0; rk[i] = 0; }
    __syncthreads();
    int base = c * CHUNK;
    int n = min(CHUNK, Ee - base);
    for (int i = t; i < n; i += 512)
        atomicAdd(&hb[((unsigned)dst[base + i]) >> DSH], 1u);
    __syncthreads();
    for (int cell = t; cell < NBKT; cell += 512) {
        unsigned cv = hb[cell];
        if (cv)   // one device atomic per (chunk, nonzero bucket): ~150K total
            bb[cell] = (unsigned)cell * STRIDE + atomicAdd(&gcnt[cell], cv);
    }
    __syncthreads();
    for (int i = t; i < n; i += 512) {
        int e = base + i;
        unsigned d = (unsigned)dst[e];
        unsigned r = (unsigned)et[e];
        unsigned sv = (unsigned)src[e];
        unsigned bkt = d >> DSH;
        unsigned rank = atomicAdd(&rk[bkt], 1u);
        rec[bb[bkt] + rank] = sv | (r << 16) | ((d & DLOWM) << 21);  // src16|rel5|dlow7
    }
}

// --- 2. per-bucket counting sort: 128 dst x 32 rel cells in LDS (512t) --------
__global__ __launch_bounds__(512) void sortD_kernel(const unsigned* __restrict__ rec,
                                                    const unsigned* __restrict__ gcnt,
                                                    unsigned* __restrict__ sorted,
                                                    int* __restrict__ offs,
                                                    unsigned short* __restrict__ deg16) {
    __shared__ unsigned cnt[128 * 33];
    __shared__ unsigned sb[128 * 33];
    __shared__ int l2s[2];
    int b = blockIdx.x, t = threadIdx.x, lane = t & 63, wv = t >> 6;
    for (int i = t; i < 128 * 33; i += 512) cnt[i] = 0;
    __syncthreads();
    unsigned rb = (unsigned)b * STRIDE;
    int n = (int)min(gcnt[b], (unsigned)STRIDE);
    for (int i = t; i < n; i += 512) {
        unsigned w = rec[rb + i];
        atomicAdd(&cnt[((w >> 21) & 127u) * 33 + ((w >> 16) & 31u)], 1u);
    }
    __syncthreads();
    int deg = 0;
    if (t < 128) {
#pragma unroll
        for (int r = 0; r < 32; ++r) {
            unsigned cc = cnt[t * 33 + r];
            sb[t * 33 + r] = (unsigned)deg;
            deg += (int)cc;
        }
    }
    int s = deg;   // waves 0-1 carry real values; others zero/unused
#pragma unroll
    for (int o = 1; o < 64; o <<= 1) { int u = __shfl_up(s, o, 64); if (lane >= o) s += u; }
    if (lane == 63 && wv < 2) l2s[wv] = s;
    __syncthreads();
    if (t < 128) {
        int excl = s - deg + (wv == 1 ? l2s[0] : 0);
        unsigned ab = rb + (unsigned)excl;
        int d = b * 128 + t;
        if (d < Nn) { offs[d] = (int)ab; deg16[d] = (unsigned short)deg; }
#pragma unroll
        for (int r = 0; r < 32; ++r) sb[t * 33 + r] += ab;
    }
    __syncthreads();
    for (int i = t; i < n; i += 512) {
        unsigned w = rec[rb + i];
        unsigned dlow = (w >> 21) & 127u, rel = (w >> 16) & 31u, sv = w & 0xFFFFu;
        int cell = (int)dlow * 33 + (int)rel;
        unsigned pos = atomicAdd(&sb[cell], 1u);
        unsigned cc = cnt[cell];
        if (cc > 2047u) cc = 2047u;
        sorted[pos] = sv | (rel << 16) | (cc << 21);
    }
}

// --- 3. layer 1: one wave per dst, 16 edges x 4 h-lanes (8B gathers) ----------
__global__ __launch_bounds__(256) void l1_kernel(const unsigned* __restrict__ sorted,
                                                 const int* __restrict__ offs,
                                                 const unsigned short* __restrict__ deg16,
                                                 const void* __restrict__ w1,
                                                 const void* __restrict__ root1,
                                                 const void* __restrict__ b1,
                                                 const int* __restrict__ flag,
                                                 float* __restrict__ x) {
    int tid = threadIdx.x, w = tid >> 6, lane = tid & 63;
    int ep = lane >> 2, hp = lane & 3;
    int isbf = *flag;
    int d = blockIdx.x * 4 + w;                  // 12500*4 == Nn
    int off = offs[d], deg = (int)deg16[d];
    float a0 = 0.f, a1 = 0.f, a2 = 0.f, a3 = 0.f;
    if (isbf) {
#pragma unroll 2
        for (int i = ep; i < deg; i += 16) {
            unsigned p = sorted[off + i];
            int cnt = p >> 21, rel = (p >> 16) & 31, s = p & 0xFFFF;
            float inv = __builtin_amdgcn_rcpf((float)cnt);
            ushort4 v = ((const ushort4*)w1)[((size_t)rel * Nn + s) * 4 + hp];
            a0 += inv * bs2f(v.x); a1 += inv * bs2f(v.y);
            a2 += inv * bs2f(v.z); a3 += inv * bs2f(v.w);
        }
    } else {
#pragma unroll 2
        for (int i = ep; i < deg; i += 16) {
            unsigned p = sorted[off + i];
            int cnt = p >> 21, rel = (p >> 16) & 31, s = p & 0xFFFF;
            float inv = __builtin_amdgcn_rcpf((float)cnt);
            float4 v = ((const float4*)w1)[((size_t)rel * Nn + s) * 4 + hp];
            a0 += inv * v.x; a1 += inv * v.y; a2 += inv * v.z; a3 += inv * v.w;
        }
    }
#pragma unroll
    for (int o = 4; o < 64; o <<= 1) {
        a0 += __shfl_xor(a0, o, 64);
        a1 += __shfl_xor(a1, o, 64);
        a2 += __shfl_xor(a2, o, 64);
        a3 += __shfl_xor(a3, o, 64);
    }
    if (ep == 0) {   // lanes 0..3 hold h = hp*4 .. hp*4+3
        float r0, r1, r2, r3, bb0, bb1, bb2, bb3;
        if (isbf) {
            ushort4 rv = ((const ushort4*)root1)[(size_t)d * 4 + hp];
            ushort4 bv = ((const ushort4*)b1)[hp];
            r0 = bs2f(rv.x); r1 = bs2f(rv.y); r2 = bs2f(rv.z); r3 = bs2f(rv.w);
            bb0 = bs2f(bv.x); bb1 = bs2f(bv.y); bb2 = bs2f(bv.z); bb3 = bs2f(bv.w);
        } else {
            float4 rv = ((const float4*)root1)[(size_t)d * 4 + hp];
            float4 bv = ((const float4*)b1)[hp];
            r0 = rv.x; r1 = rv.y; r2 = rv.z; r3 = rv.w;
            bb0 = bv.x; bb1 = bv.y; bb2 = bv.z; bb3 = bv.w;
        }
        float v0 = a0 + r0 + bb0, v1 = a1 + r1 + bb1;
        float v2 = a2 + r2 + bb2, v3 = a3 + r3 + bb3;
        *(float4*)(x + (size_t)d * Hh + hp * 4) =
            make_float4(v0 > 0.f ? v0 : 0.f, v1 > 0.f ? v1 : 0.f,
                        v2 > 0.f ? v2 : 0.f, v3 > 0.f ? v3 : 0.f);
    }
}

// --- 4. layer 2 + epilogue: block owns 16 dsts; wave loops 4 dsts -------------
// (r9 inner loop: 8 edges x 8 classes, reg dots; staging amortized 4x)
__global__ __launch_bounds__(256) void l2_kernel(const unsigned* __restrict__ sorted,
                                                 const int* __restrict__ offs,
                                                 const unsigned short* __restrict__ deg16,
                                                 const float* __restrict__ x,
                                                 const void* __restrict__ w2,
                                                 const void* __restrict__ root2,
                                                 const void* __restrict__ b2v,
                                                 const int* __restrict__ flag,
                                                 void* __restrict__ out) {
    __shared__ float w2s[32 * 132];   // [rel]*132 + c*16 + h  (pad 132: ~2-way banks)
    __shared__ float rsh[128];        // root2 [h*8+c]
    __shared__ float b2sh[8];
    int tid = threadIdx.x, w = tid >> 6, lane = tid & 63;
    int isbf = *flag;
    {
        int r = tid >> 3, cc = tid & 7;
        if (isbf) {
            const __hip_bfloat16* W = (const __hip_bfloat16*)w2 + r * 128 + cc;
#pragma unroll
            for (int h = 0; h < 16; ++h) w2s[r * 132 + cc * 16 + h] = b2f(W[h * 8]);
        } else {
            const float* W = (const float*)w2 + r * 128 + cc;
#pragma unroll
            for (int h = 0; h < 16; ++h) w2s[r * 132 + cc * 16 + h] = W[h * 8];
        }
    }
    if (tid < 128) rsh[tid] = isbf ? b2f(((const __hip_bfloat16*)root2)[tid])
                                   : ((const float*)root2)[tid];
    if (tid < 8)   b2sh[tid] = isbf ? b2f(((const __hip_bfloat16*)b2v)[tid])
                                    : ((const float*)b2v)[tid];
    __syncthreads();
    int ep = lane >> 3, c = lane & 7;
    int d0 = blockIdx.x * 16 + w * 4;            // 3125*16 == Nn; wave w: 4 dsts
    for (int j = 0; j < 4; ++j) {
        int d = d0 + j;
        int off = offs[d], deg = (int)deg16[d];
        float acc = 0.0f;
        for (int i0 = 0; i0 < deg; i0 += 8) {
            int i = i0 + ep;
            if (i < deg) {
                unsigned p = sorted[off + i];
                int cnt = p >> 21, rel = (p >> 16) & 31, s = p & 0xFFFF;
                float inv = __builtin_amdgcn_rcpf((float)cnt);
                const float4* xr = (const float4*)(x + (size_t)s * Hh);
                float4 x0 = xr[0], x1 = xr[1], x2 = xr[2], x3 = xr[3];
                const float4* wv = (const float4*)(w2s + rel * 132 + c * 16);
                float4 w0 = wv[0], w1v = wv[1], w2v = wv[2], w3 = wv[3];
                float dot = x0.x*w0.x + x0.y*w0.y + x0.z*w0.z + x0.w*w0.w
                          + x1.x*w1v.x + x1.y*w1v.y + x1.z*w1v.z + x1.w*w1v.w
                          + x2.x*w2v.x + x2.y*w2v.y + x2.z*w2v.z + x2.w*w2v.w
                          + x3.x*w3.x + x3.y*w3.y + x3.z*w3.z + x3.w*w3.w;
                acc += inv * dot;
            }
        }
        acc += __shfl_xor(acc, 8, 64);
        acc += __shfl_xor(acc, 16, 64);
        acc += __shfl_xor(acc, 32, 64);
        if (ep == 0) {
            const float4* xr = (const float4*)(x + (size_t)d * Hh);
            float4 x0 = xr[0], x1 = xr[1], x2 = xr[2], x3 = xr[3];
            float xv[16] = {x0.x,x0.y,x0.z,x0.w, x1.x,x1.y,x1.z,x1.w,
                            x2.x,x2.y,x2.z,x2.w, x3.x,x3.y,x3.z,x3.w};
            float v = acc + b2sh[c];
#pragma unroll
            for (int h = 0; h < 16; ++h) v += xv[h] * rsh[h * 8 + c];
            float m = v;
#pragma unroll
            for (int o = 1; o < 8; o <<= 1) m = fmaxf(m, __shfl_xor(m, o, 8));
            float ssum = __expf(v - m);
#pragma unroll
            for (int o = 1; o < 8; o <<= 1) ssum += __shfl_xor(ssum, o, 8);
            float res = v - m - __logf(ssum);
            if (isbf) ((__hip_bfloat16*)out)[(size_t)d * Cc + c] = __float2bfloat16(res);
            else      ((float*)out)[(size_t)d * Cc + c] = res;
        }
    }
}

extern "C" void kernel_launch(void* const* d_in, const int* in_sizes, int n_in,
                              void* d_out, int out_size, void* d_ws, size_t ws_size,
                              hipStream_t stream) {
    const int* edge_index = (const int*)d_in[0];     // [2, E]
    const int* src = edge_index;
    const int* dst = edge_index + Ee;
    const int* et  = (const int*)d_in[1];            // [E]
    const void* w1    = d_in[2];  // [R,N,H]
    const void* root1 = d_in[3];  // [N,H]
    const void* b1    = d_in[4];  // [H]
    const void* w2    = d_in[5];  // [R,H,C]
    const void* root2 = d_in[6];  // [H,C]
    const void* b2    = d_in[7];  // [C]

    // ws (u32 words, ~16.3 MB): rec[NBKT*STRIDE] (x[800000] overlays after
    // sortD) | sorted[NBKT*STRIDE] | gcnt[NBKT] | offs[Nn] | deg16[Nn u16] |
    // flag. Only gcnt needs zeroing (1.6 KB).
    unsigned* rec    = (unsigned*)d_ws;
    unsigned* sorted = rec + (size_t)NBKT * STRIDE;
    unsigned* gcnt   = sorted + (size_t)NBKT * STRIDE;
    int* offs        = (int*)(gcnt + NBKT);
    unsigned short* deg16 = (unsigned short*)(offs + Nn);
    int* flag        = (int*)(deg16 + Nn + 2);
    float* x         = (float*)rec;    // overlay: rec dead after sortD

    hipMemsetAsync(gcnt, 0, NBKT * sizeof(unsigned), stream);
    scat_kernel<<<NC, 512, 0, stream>>>(src, dst, et, gcnt, rec,
                                        (const unsigned short*)w1, flag);
    sortD_kernel<<<NBKT, 512, 0, stream>>>(rec, gcnt, sorted, offs, deg16);
    l1_kernel<<<Nn / 4, 256, 0, stream>>>(sorted, offs, deg16, w1, root1, b1, flag, x);
    l2_kernel<<<Nn / 16, 256, 0, stream>>>(sorted, offs, deg16, x, w2, root2, b2, flag, d_out);
}